// Round 6
// baseline (898.796 us; speedup 1.0000x reference)
//
#include <hip/hip_runtime.h>

#define NN 100000      // nodes per type (authors == papers == 100000)
#define NE 500000      // edges per relation
#define HD 128         // hidden
#define NBLK 391       // ceil(NN/256)

typedef float f32x4v __attribute__((ext_vector_type(4)));
typedef short s16x8  __attribute__((ext_vector_type(8)));

// float -> bf16 bits, RNE
static __device__ __forceinline__ unsigned f2bf_bits(float f){
  unsigned u = __float_as_uint(f);
  return (u + 0x7FFF + ((u >> 16) & 1)) >> 16;
}

static __device__ __forceinline__ void split8(const float* a, s16x8& hi, s16x8& lo){
  #pragma unroll
  for (int j = 0; j < 8; ++j){
    float f = a[j];
    unsigned hb = f2bf_bits(f);
    float hf = __uint_as_float(hb << 16);
    float lf = f - hf;
    hi[j] = (short)hb;
    lo[j] = (short)f2bf_bits(lf);
  }
}

static __device__ __forceinline__ float4 bn_lrelu4(float4 v, float4 sc, float4 sh){
  v.x = v.x*sc.x + sh.x; v.x = v.x >= 0.f ? v.x : 0.01f*v.x;
  v.y = v.y*sc.y + sh.y; v.y = v.y >= 0.f ? v.y : 0.01f*v.y;
  v.z = v.z*sc.z + sh.z; v.z = v.z >= 0.f ? v.z : 0.01f*v.z;
  v.w = v.w*sc.w + sh.w; v.w = v.w >= 0.f ? v.w : 0.01f*v.w;
  return v;
}

// ============================ CSR build =================================
__global__ void k_count(const int* __restrict__ ei_pa, const int* __restrict__ ei_ap,
                        int* __restrict__ deg2){
  int idx = blockIdx.x * 256 + threadIdx.x;
  if (idx < NE)        atomicAdd(&deg2[      ei_pa[NE + idx]], 1);
  else if (idx < 2*NE) atomicAdd(&deg2[NN + ei_ap[NE + (idx - NE)]], 1);
}

__global__ void k_bsum(const int* __restrict__ deg2, int* __restrict__ bsum){
  int rel = blockIdx.x / NBLK, b = blockIdx.x % NBLK;
  int i = b*256 + threadIdx.x;
  int v = (i < NN) ? deg2[rel*NN + i] : 0;
  __shared__ int s[256];
  s[threadIdx.x] = v; __syncthreads();
  for (int o = 128; o > 0; o >>= 1){
    if (threadIdx.x < o) s[threadIdx.x] += s[threadIdx.x + o];
    __syncthreads();
  }
  if (threadIdx.x == 0) bsum[rel*512 + b] = s[0];
}

__global__ void k_bscan(const int* __restrict__ bsum, int* __restrict__ bsoff){
  int rel = blockIdx.x, t = threadIdx.x;
  int v = (t < NBLK) ? bsum[rel*512 + t] : 0;
  __shared__ int s[512];
  s[t] = v; __syncthreads();
  for (int o = 1; o < 512; o <<= 1){
    int x = (t >= o) ? s[t - o] : 0;
    __syncthreads();
    s[t] += x;
    __syncthreads();
  }
  bsoff[rel*512 + t] = s[t] - v;   // exclusive
}

__global__ void k_scanC(const int* __restrict__ deg2, const int* __restrict__ bsoff,
                        int* __restrict__ off2, int* __restrict__ cur2){
  int rel = blockIdx.x / NBLK, b = blockIdx.x % NBLK;
  int i = b*256 + threadIdx.x, t = threadIdx.x;
  int v = (i < NN) ? deg2[rel*NN + i] : 0;
  __shared__ int s[256];
  s[t] = v; __syncthreads();
  for (int o = 1; o < 256; o <<= 1){
    int x = (t >= o) ? s[t - o] : 0;
    __syncthreads();
    s[t] += x;
    __syncthreads();
  }
  if (i < NN){
    int o = bsoff[rel*512 + b] + s[t] - v;
    off2[rel*NN + i] = o;
    cur2[rel*NN + i] = o;
  }
}

__global__ void k_fill(const int* __restrict__ ei_pa, const int* __restrict__ ei_ap,
                       int* __restrict__ cur2,
                       int* __restrict__ col_pa, int* __restrict__ col_ap){
  int idx = blockIdx.x * 256 + threadIdx.x;
  if (idx < NE){
    int s = ei_pa[idx], d = ei_pa[NE + idx];
    int pos = atomicAdd(&cur2[d], 1);
    col_pa[pos] = s;
  } else if (idx < 2*NE){
    int e = idx - NE;
    int s = ei_ap[e], d = ei_ap[NE + e];
    int pos = atomicAdd(&cur2[NN + d], 1);
    col_ap[pos] = s;
  }
}

// ============================ weight folding ============================
// W' = A(128-col rows) @ B(wu half) -> bf16 hi/lo MFMA B-fragments at
// k-chunk offset `off`: elem = ((gkc*8+nt)*2+h)*512 + lane*8 + j,
// lane = quad*16 + (n&15), k = gkc*32 + quad*8 + j.
struct FoldDesc { const float* A; const float* B; short* T; int off; };
struct FoldArgs { FoldDesc d[8]; int rs[9]; };

__global__ void k_fold(FoldArgs fa){
  int row = blockIdx.x;
  int seg = 0;
  #pragma unroll
  for (int s = 0; s < 8; ++s) if (row >= fa.rs[s+1]) seg = s + 1;
  int m = row - fa.rs[seg];             // local k index of W'
  const float* A = fa.d[seg].A + (size_t)m * 128;
  const float* B = fa.d[seg].B;
  int n = threadIdx.x;
  float acc = 0.f;
  for (int k = 0; k < 128; ++k) acc += A[k] * B[k*128 + n];
  unsigned hb = f2bf_bits(acc);
  float hf = __uint_as_float(hb << 16);
  unsigned lb = f2bf_bits(acc - hf);
  int gkc = fa.d[seg].off + (m >> 5), quad = (m >> 3) & 3, j = m & 7;
  int lane = quad*16 + (n & 15), nt = n >> 4;
  size_t fb = (size_t)((gkc*8 + nt)*2)*512 + lane*8 + j;
  fa.d[seg].T[fb]       = (short)hb;
  fa.d[seg].T[fb + 512] = (short)lb;
}

// b' = bd@wu_top + bs@wu_bot + bu
struct BiasArgs { const float* bd[4]; const float* bs[4]; const float* wu[4];
                  const float* bu[4]; float* outb[4]; };
__global__ void k_biasfold(BiasArgs ba){
  int s = blockIdx.x, j = threadIdx.x;
  const float* wu = ba.wu[s];
  float acc = ba.bu[s][j];
  for (int k = 0; k < 128; ++k)
    acc += ba.bd[s][k] * wu[k*128 + j] + ba.bs[s][k] * wu[(128 + k)*128 + j];
  ba.outb[s][j] = acc;
}

// ============================ MFMA GEMM =================================
// C[M,128] = bnlrelu?(A1)[:,0:KC1*32] @ B[0:KC1] + A2 @ B[KC1:] (+bias)
// (+extra). B staged to LDS in 2-kc groups (32 KB -> 4 blocks/CU). A register
// double-buffered. Epilogue: per-wave 16-row LDS slab transpose w/ chunk
// rotation (2-way max bank alias = free); coalesced float4 stores; optional
// fused BN column stats.
__global__ __launch_bounds__(256, 4)
void k_gemm2(const float* __restrict__ A1, int lda1, int KC1,
             const float* __restrict__ bn1,
             const float* __restrict__ A2, int lda2, int KC2,
             const short* __restrict__ Bf,
             const float* __restrict__ bias, const float* __restrict__ extra,
             float* __restrict__ C, float* __restrict__ stats, int M)
{
  __shared__ __align__(16) char smem[32768];
  short* Bs = (short*)smem;

  const int tid  = threadIdx.x;
  const int wave = tid >> 6, lane = tid & 63;
  const int li   = lane & 15, quad = lane >> 4;
  const int rowT = blockIdx.x * 128 + wave * 32;
  const int KCtot = KC1 + KC2;

  f32x4v acc[2][8];
  #pragma unroll
  for (int mt = 0; mt < 2; ++mt)
    #pragma unroll
    for (int nt = 0; nt < 8; ++nt)
      acc[mt][nt] = (f32x4v){0.f, 0.f, 0.f, 0.f};

  float4 c0[2], c1[2], n0[2], n1[2];
  auto loadA = [&](int gkc, float4* p0, float4* p1){
    const float* Ab; int ld, kk; bool bn;
    if (gkc < KC1){ Ab = A1; ld = lda1; kk = gkc; bn = (bn1 != nullptr); }
    else          { Ab = A2; ld = lda2; kk = gkc - KC1; bn = false; }
    float4 sc0, sc1, sh0, sh1;
    if (bn){
      const float* bsc = bn1 + kk*32 + quad*8;
      sc0 = *(const float4*)bsc;        sc1 = *(const float4*)(bsc + 4);
      sh0 = *(const float4*)(bsc+128);  sh1 = *(const float4*)(bsc + 132);
    }
    #pragma unroll
    for (int mt = 0; mt < 2; ++mt){
      int row = rowT + mt*16 + li;
      if (row < M){
        const float* ap = Ab + (size_t)row*ld + kk*32 + quad*8;
        float4 v0 = *(const float4*)ap;
        float4 v1 = *(const float4*)(ap + 4);
        if (bn){ v0 = bn_lrelu4(v0, sc0, sh0); v1 = bn_lrelu4(v1, sc1, sh1); }
        p0[mt] = v0; p1[mt] = v1;
      } else {
        p0[mt] = make_float4(0.f,0.f,0.f,0.f);
        p1[mt] = make_float4(0.f,0.f,0.f,0.f);
      }
    }
  };
  loadA(0, c0, c1);

  for (int g = 0; g < KCtot; g += 2){
    if (g > 0) __syncthreads();          // prior group's LDS reads done
    const short* src = Bf + (size_t)g*8192;
    #pragma unroll
    for (int c2 = 0; c2 < 8; ++c2){
      int id = c2*256 + tid;             // chunk of 8 shorts, 0..2047
      *(s16x8*)(Bs + id*8) = *(const s16x8*)(src + id*8);
    }
    __syncthreads();
    #pragma unroll
    for (int kc = 0; kc < 2; ++kc){
      int gkc = g + kc;
      if (gkc + 1 < KCtot) loadA(gkc + 1, n0, n1);
      s16x8 ah[2], al[2];
      #pragma unroll
      for (int mt = 0; mt < 2; ++mt){
        float av[8] = {c0[mt].x, c0[mt].y, c0[mt].z, c0[mt].w,
                       c1[mt].x, c1[mt].y, c1[mt].z, c1[mt].w};
        split8(av, ah[mt], al[mt]);
      }
      #pragma unroll
      for (int nt = 0; nt < 8; ++nt){
        const short* bp = Bs + ((kc*8 + nt) << 10) + lane*8;
        s16x8 bh = *(const s16x8*)bp;
        s16x8 bl = *(const s16x8*)(bp + 512);
        #pragma unroll
        for (int mt = 0; mt < 2; ++mt){
          acc[mt][nt] = __builtin_amdgcn_mfma_f32_16x16x32_bf16(ah[mt], bh, acc[mt][nt], 0, 0, 0);
          acc[mt][nt] = __builtin_amdgcn_mfma_f32_16x16x32_bf16(al[mt], bh, acc[mt][nt], 0, 0, 0);
          acc[mt][nt] = __builtin_amdgcn_mfma_f32_16x16x32_bf16(ah[mt], bl, acc[mt][nt], 0, 0, 0);
        }
      }
      #pragma unroll
      for (int mt = 0; mt < 2; ++mt){ c0[mt] = n0[mt]; c1[mt] = n1[mt]; }
    }
  }

  // ---- epilogue: per-wave 16-row slab transpose (8 KB/wave) ----
  __syncthreads();                       // all LDS B reads done
  float* Cw = (float*)smem + wave*2048;  // wave-private slab
  int col4 = lane & 31;
  float4 bias4 = make_float4(0.f,0.f,0.f,0.f);
  if (bias) bias4 = ((const float4*)bias)[col4];
  float4 s1 = make_float4(0.f,0.f,0.f,0.f), s2 = s1;
  #pragma unroll
  for (int mt = 0; mt < 2; ++mt){
    #pragma unroll
    for (int r = 0; r < 4; ++r){
      int lr = quad*4 + r;               // local row 0..15
      #pragma unroll
      for (int nt = 0; nt < 8; ++nt){
        int c = nt*16 + li;
        int chunk = ((c >> 2) + 2*quad) & 31;   // rotation kills 4-way conflict
        Cw[lr*128 + chunk*4 + (c & 3)] = acc[mt][nt][r];
      }
    }
    // read back (intra-wave dependence only)
    #pragma unroll
    for (int i = 0; i < 8; ++i){
      int lr = i*2 + (lane >> 5);
      int grow = rowT + mt*16 + lr;
      if (grow >= M) continue;
      int chunk = (col4 + 2*(lr >> 2)) & 31;
      float4 v = *(const float4*)(Cw + lr*128 + chunk*4);
      v.x += bias4.x; v.y += bias4.y; v.z += bias4.z; v.w += bias4.w;
      if (extra){
        float4 e = ((const float4*)(extra + (size_t)grow*128))[col4];
        v.x += e.x; v.y += e.y; v.z += e.z; v.w += e.w;
      }
      ((float4*)(C + (size_t)grow*128))[col4] = v;
      s1.x += v.x; s1.y += v.y; s1.z += v.z; s1.w += v.w;
      s2.x += v.x*v.x; s2.y += v.y*v.y; s2.z += v.z*v.z; s2.w += v.w*v.w;
    }
  }
  if (stats){
    __syncthreads();               // slabs dead; reuse smem for partials
    float* Ss = (float*)smem;      // [256 threads][8]: s1.xyzw, s2.xyzw
    ((float4*)Ss)[tid*2]     = s1;
    ((float4*)Ss)[tid*2 + 1] = s2;
    __syncthreads();
    int c = tid & 127, kind = tid >> 7;     // kind 0 = sum, 1 = sumsq
    int cc4 = c >> 2, comp = c & 3;
    float s = 0.f;
    #pragma unroll
    for (int wv = 0; wv < 4; ++wv)
      #pragma unroll
      for (int hf = 0; hf < 2; ++hf)
        s += Ss[(wv*64 + hf*32 + cc4)*8 + kind*4 + comp];
    atomicAdd(&stats[kind*128 + c], s);
  }
}

// ============================ mean-aggregate ============================
// 8 dst/block, 32 float4-lanes per dst; 4-edge unroll; optional fused
// BN+lrelu applied per gathered source row.
__global__ __launch_bounds__(256)
void k_agg(const float* __restrict__ t, const int* __restrict__ off,
           const int* __restrict__ deg, const int* __restrict__ col,
           float* __restrict__ o, const float* __restrict__ bn){
  int slot = threadIdx.x >> 5, col4 = threadIdx.x & 31;
  int d = blockIdx.x*8 + slot;
  if (d >= NN) return;
  float4 sc4, sh4;
  bool hasbn = (bn != nullptr);
  if (hasbn){ sc4 = ((const float4*)bn)[col4]; sh4 = ((const float4*)(bn+128))[col4]; }
  int s0 = off[d], cnt = deg[d];
  float4 a0 = make_float4(0.f,0.f,0.f,0.f), a1 = a0;
  int i = 0;
  for (; i + 4 <= cnt; i += 4){
    int sa = col[s0+i], sb = col[s0+i+1], sct = col[s0+i+2], sd = col[s0+i+3];
    float4 v0 = ((const float4*)(t + (size_t)sa*128))[col4];
    float4 v1 = ((const float4*)(t + (size_t)sb*128))[col4];
    float4 v2 = ((const float4*)(t + (size_t)sct*128))[col4];
    float4 v3 = ((const float4*)(t + (size_t)sd*128))[col4];
    if (hasbn){
      v0 = bn_lrelu4(v0, sc4, sh4); v1 = bn_lrelu4(v1, sc4, sh4);
      v2 = bn_lrelu4(v2, sc4, sh4); v3 = bn_lrelu4(v3, sc4, sh4);
    }
    a0.x += v0.x + v2.x; a0.y += v0.y + v2.y; a0.z += v0.z + v2.z; a0.w += v0.w + v2.w;
    a1.x += v1.x + v3.x; a1.y += v1.y + v3.y; a1.z += v1.z + v3.z; a1.w += v1.w + v3.w;
  }
  for (; i < cnt; ++i){
    int sa = col[s0+i];
    float4 v0 = ((const float4*)(t + (size_t)sa*128))[col4];
    if (hasbn) v0 = bn_lrelu4(v0, sc4, sh4);
    a0.x += v0.x; a0.y += v0.y; a0.z += v0.z; a0.w += v0.w;
  }
  float inv = 1.0f / (float)(cnt > 0 ? cnt : 1);
  float4 r;
  r.x = (a0.x + a1.x)*inv; r.y = (a0.y + a1.y)*inv;
  r.z = (a0.z + a1.z)*inv; r.w = (a0.w + a1.w)*inv;
  ((float4*)(o + (size_t)d*128))[col4] = r;
}

// ============================ batchnorm prep ============================
__global__ void k_bnprep(const float* __restrict__ stats, const float* __restrict__ g,
                         const float* __restrict__ b, float* __restrict__ sc, int M){
  int c = threadIdx.x;
  float invN = 1.0f / (float)M;
  float m  = stats[c] * invN;
  float var = stats[128 + c] * invN - m*m;
  float scale = g[c] / sqrtf(var + 1.0f);
  sc[c] = scale;
  sc[128 + c] = b[c] - m*scale;
}

// ============================ heads (fused BN+lrelu) ====================
template<int LC>
__global__ void k_head(const float* __restrict__ h, const float* __restrict__ bn,
                       const float* __restrict__ w, const float* __restrict__ b,
                       float* __restrict__ o, int M){
  __shared__ float ws[128*LC];
  __shared__ float bs[LC];
  __shared__ float bsc[256];
  for (int i = threadIdx.x; i < 128*LC; i += 256) ws[i] = w[i];
  if (threadIdx.x < LC) bs[threadIdx.x] = b[threadIdx.x];
  if (threadIdx.x < 256) bsc[threadIdx.x] = bn[threadIdx.x];
  __syncthreads();
  int r = blockIdx.x*256 + threadIdx.x;
  if (r >= M) return;
  float acc[LC];
  #pragma unroll
  for (int c = 0; c < LC; ++c) acc[c] = bs[c];
  const float4* hr = (const float4*)(h + (size_t)r*128);
  for (int k4 = 0; k4 < 32; ++k4){
    float4 v = hr[k4];
    float4 sc = ((const float4*)bsc)[k4];
    float4 sh = ((const float4*)bsc)[32 + k4];
    v = bn_lrelu4(v, sc, sh);
    int k = k4*4;
    #pragma unroll
    for (int c = 0; c < LC; ++c)
      acc[c] += v.x*ws[k*LC+c] + v.y*ws[(k+1)*LC+c] + v.z*ws[(k+2)*LC+c] + v.w*ws[(k+3)*LC+c];
  }
  #pragma unroll
  for (int c = 0; c < LC; ++c) o[(size_t)r*LC + c] = acc[c];
}

// ============================ launch ====================================
extern "C" void kernel_launch(void* const* d_in, const int* in_sizes, int n_in,
                              void* d_out, int out_size, void* d_ws, size_t ws_size,
                              hipStream_t stream) {
  const float* x_author = (const float*)d_in[0];   // [NN,256]
  const float* x_paper  = (const float*)d_in[1];   // [NN,128]
  const int*   ei_pa    = (const int*)d_in[2];     // [2,NE]
  const int*   ei_ap    = (const int*)d_in[3];     // [2,NE]

  char* p = (char*)d_ws;
  auto alloc = [&](size_t bytes) -> void* {
    void* r = (void*)p; p += (bytes + 255) & ~(size_t)255; return r;
  };
  // combined fragment tables (bf16 hi/lo, 16 KB per k-chunk):
  short* T_l1a  = (short*)alloc(12u*16384);  // [x_author(8) | agg_pa(4)]
  short* T_l1ps = (short*)alloc( 8u*16384);  // src transform: x_author @ Ws'
  short* T_l1pd = (short*)alloc( 4u*16384);  // dst: x_paper @ Wd'
  short* T_l2a  = (short*)alloc( 8u*16384);  // [h_a(4) | agg(4)]
  short* T_l2p  = (short*)alloc( 8u*16384);
  float* w1a_b = (float*)alloc(128*4);      float* w1p_b = (float*)alloc(128*4);
  float* w2a_b = (float*)alloc(128*4);      float* w2p_b = (float*)alloc(128*4);
  float* stats4 = (float*)alloc(4*256*4);   // 4 BN instances (sum/sumsq)
  float* bnsc4  = (float*)alloc(4*256*4);   // 4 BN instances (scale/shift)
  int* deg2  = (int*)alloc(2*NN*4);
  int* off2  = (int*)alloc(2*NN*4);
  int* cur2  = (int*)alloc(2*NN*4);
  int* col_pa = (int*)alloc(NE*4);
  int* col_ap = (int*)alloc(NE*4);
  int* bsum  = (int*)alloc(1024*4);
  int* bsoff = (int*)alloc(1024*4);
  const size_t NB = (size_t)NN * 128;
  float* B1 = (float*)alloc(NB*4);  // h_author L1 (pre-BN)
  float* B2 = (float*)alloc(NB*4);  // h_paper L1 (pre-BN)
  float* B3 = (float*)alloc(NB*4);  // src transform (l1p) / h_a2 / h_p2
  float* B4 = (float*)alloc(NB*4);  // agg buffer

  // ---- CSR build ----
  hipMemsetAsync(deg2, 0, 2*NN*4, stream);
  hipMemsetAsync(stats4, 0, 4*256*4, stream);
  k_count<<<(2*NE + 255)/256, 256, 0, stream>>>(ei_pa, ei_ap, deg2);
  k_bsum <<<2*NBLK, 256, 0, stream>>>(deg2, bsum);
  k_bscan<<<2, 512, 0, stream>>>(bsum, bsoff);
  k_scanC<<<2*NBLK, 256, 0, stream>>>(deg2, bsoff, off2, cur2);
  k_fill <<<(2*NE + 255)/256, 256, 0, stream>>>(ei_pa, ei_ap, cur2, col_pa, col_ap);

  // ---- fold weights into combined tables ----
  FoldArgs fa;
  const float* wu1a = (const float*)d_in[8];
  const float* wu1p = (const float*)d_in[14];
  const float* wu2a = (const float*)d_in[20];
  const float* wu2p = (const float*)d_in[26];
  fa.d[0] = { (const float*)d_in[6],  wu1a,           T_l1a,  0 };  // wd_l1a (256)
  fa.d[1] = { (const float*)d_in[4],  wu1a + 128*128, T_l1a,  8 };  // ws_l1a (128)
  fa.d[2] = { (const float*)d_in[10], wu1p + 128*128, T_l1ps, 0 };  // ws_l1p (256)
  fa.d[3] = { (const float*)d_in[12], wu1p,           T_l1pd, 0 };  // wd_l1p (128)
  fa.d[4] = { (const float*)d_in[18], wu2a,           T_l2a,  0 };  // wd_l2a (128)
  fa.d[5] = { (const float*)d_in[16], wu2a + 128*128, T_l2a,  4 };  // ws_l2a (128)
  fa.d[6] = { (const float*)d_in[24], wu2p,           T_l2p,  0 };  // wd_l2p (128)
  fa.d[7] = { (const float*)d_in[22], wu2p + 128*128, T_l2p,  4 };  // ws_l2p (128)
  int rows[8] = {256,128,256,128,128,128,128,128};
  fa.rs[0] = 0;
  for (int i = 0; i < 8; ++i) fa.rs[i+1] = fa.rs[i] + rows[i];
  k_fold<<<fa.rs[8], 128, 0, stream>>>(fa);

  BiasArgs ba;
  ba.bd[0]=(const float*)d_in[7];  ba.bs[0]=(const float*)d_in[5];  ba.wu[0]=wu1a; ba.bu[0]=(const float*)d_in[9];  ba.outb[0]=w1a_b;
  ba.bd[1]=(const float*)d_in[13]; ba.bs[1]=(const float*)d_in[11]; ba.wu[1]=wu1p; ba.bu[1]=(const float*)d_in[15]; ba.outb[1]=w1p_b;
  ba.bd[2]=(const float*)d_in[19]; ba.bs[2]=(const float*)d_in[17]; ba.wu[2]=wu2a; ba.bu[2]=(const float*)d_in[21]; ba.outb[2]=w2a_b;
  ba.bd[3]=(const float*)d_in[25]; ba.bs[3]=(const float*)d_in[23]; ba.wu[3]=wu2p; ba.bu[3]=(const float*)d_in[27]; ba.outb[3]=w2p_b;
  k_biasfold<<<4, 128, 0, stream>>>(ba);

  const int GG = (NN + 127)/128;   // 782
  const int AGG_GRID = (NN + 7)/8; // 12500
  const int* off_pa = off2;        const int* deg_pa = deg2;
  const int* off_ap = off2 + NN;   const int* deg_ap = deg2 + NN;
  float* st_a1 = stats4;       float* st_p1 = stats4 + 256;
  float* st_a2 = stats4 + 512; float* st_p2 = stats4 + 768;
  float* sc_a1 = bnsc4;        float* sc_p1 = bnsc4 + 256;
  float* sc_a2 = bnsc4 + 512;  float* sc_p2 = bnsc4 + 768;

  // ---- layer 1, author (p2a): agg-first ----
  k_agg<<<AGG_GRID, 256, 0, stream>>>(x_paper, off_pa, deg_pa, col_pa, B4, nullptr);
  k_gemm2<<<GG, 256, 0, stream>>>(x_author, 256, 8, nullptr, B4, 128, 4, T_l1a,
                                  w1a_b, nullptr, B1, st_a1, NN);
  k_bnprep<<<1, 128, 0, stream>>>(st_a1, (const float*)d_in[28], (const float*)d_in[29], sc_a1, NN);

  // ---- layer 1, paper (a2p): transform-first (src is 256-wide) ----
  k_gemm2<<<GG, 256, 0, stream>>>(x_author, 256, 8, nullptr, nullptr, 0, 0, T_l1ps,
                                  nullptr, nullptr, B3, nullptr, NN);
  k_agg<<<AGG_GRID, 256, 0, stream>>>(B3, off_ap, deg_ap, col_ap, B4, nullptr);
  k_gemm2<<<GG, 256, 0, stream>>>(x_paper, 128, 4, nullptr, nullptr, 0, 0, T_l1pd,
                                  w1p_b, B4, B2, st_p1, NN);
  k_bnprep<<<1, 128, 0, stream>>>(st_p1, (const float*)d_in[30], (const float*)d_in[31], sc_p1, NN);

  // ---- layer 2, author (p2a): agg-first on bn(h_paper) ----
  k_agg<<<AGG_GRID, 256, 0, stream>>>(B2, off_pa, deg_pa, col_pa, B4, sc_p1);
  k_gemm2<<<GG, 256, 0, stream>>>(B1, 128, 4, sc_a1, B4, 128, 4, T_l2a,
                                  w2a_b, nullptr, B3, st_a2, NN);
  k_bnprep<<<1, 128, 0, stream>>>(st_a2, (const float*)d_in[32], (const float*)d_in[33], sc_a2, NN);
  k_head<4><<<(NN + 255)/256, 256, 0, stream>>>(B3, sc_a2, (const float*)d_in[36],
                                                (const float*)d_in[37], (float*)d_out, NN);

  // ---- layer 2, paper (a2p): agg-first on bn(h_author) ----
  k_agg<<<AGG_GRID, 256, 0, stream>>>(B1, off_ap, deg_ap, col_ap, B4, sc_a1);
  k_gemm2<<<GG, 256, 0, stream>>>(B2, 128, 4, sc_p1, B4, 128, 4, T_l2p,
                                  w2p_b, nullptr, B3, st_p2, NN);
  k_bnprep<<<1, 128, 0, stream>>>(st_p2, (const float*)d_in[34], (const float*)d_in[35], sc_p2, NN);
  k_head<7><<<(NN + 255)/256, 256, 0, stream>>>(B3, sc_p2, (const float*)d_in[38],
                                                (const float*)d_in[39], (float*)d_out + (size_t)NN*4, NN);
}

// Round 7
// 864.861 us; speedup vs baseline: 1.0392x; 1.0392x over previous
//
#include <hip/hip_runtime.h>

#define NN 100000      // nodes per type (authors == papers == 100000)
#define NE 500000      // edges per relation
#define HD 128         // hidden
#define NBLK 391       // ceil(NN/256)

typedef float f32x4v __attribute__((ext_vector_type(4)));
typedef short s16x8  __attribute__((ext_vector_type(8)));

// float -> bf16 bits, RNE
static __device__ __forceinline__ unsigned f2bf_bits(float f){
  unsigned u = __float_as_uint(f);
  return (u + 0x7FFF + ((u >> 16) & 1)) >> 16;
}

static __device__ __forceinline__ void split8(const float* a, s16x8& hi, s16x8& lo){
  #pragma unroll
  for (int j = 0; j < 8; ++j){
    float f = a[j];
    unsigned hb = f2bf_bits(f);
    float hf = __uint_as_float(hb << 16);
    float lf = f - hf;
    hi[j] = (short)hb;
    lo[j] = (short)f2bf_bits(lf);
  }
}

static __device__ __forceinline__ float4 bn_lrelu4(float4 v, float4 sc, float4 sh){
  v.x = v.x*sc.x + sh.x; v.x = v.x >= 0.f ? v.x : 0.01f*v.x;
  v.y = v.y*sc.y + sh.y; v.y = v.y >= 0.f ? v.y : 0.01f*v.y;
  v.z = v.z*sc.z + sh.z; v.z = v.z >= 0.f ? v.z : 0.01f*v.z;
  v.w = v.w*sc.w + sh.w; v.w = v.w >= 0.f ? v.w : 0.01f*v.w;
  return v;
}

// ============================ CSR build =================================
__global__ void k_count(const int* __restrict__ ei_pa, const int* __restrict__ ei_ap,
                        int* __restrict__ deg2){
  int idx = blockIdx.x * 256 + threadIdx.x;
  if (idx < NE)        atomicAdd(&deg2[      ei_pa[NE + idx]], 1);
  else if (idx < 2*NE) atomicAdd(&deg2[NN + ei_ap[NE + (idx - NE)]], 1);
}

__global__ void k_bsum(const int* __restrict__ deg2, int* __restrict__ bsum){
  int rel = blockIdx.x / NBLK, b = blockIdx.x % NBLK;
  int i = b*256 + threadIdx.x;
  int v = (i < NN) ? deg2[rel*NN + i] : 0;
  __shared__ int s[256];
  s[threadIdx.x] = v; __syncthreads();
  for (int o = 128; o > 0; o >>= 1){
    if (threadIdx.x < o) s[threadIdx.x] += s[threadIdx.x + o];
    __syncthreads();
  }
  if (threadIdx.x == 0) bsum[rel*512 + b] = s[0];
}

__global__ void k_bscan(const int* __restrict__ bsum, int* __restrict__ bsoff){
  int rel = blockIdx.x, t = threadIdx.x;
  int v = (t < NBLK) ? bsum[rel*512 + t] : 0;
  __shared__ int s[512];
  s[t] = v; __syncthreads();
  for (int o = 1; o < 512; o <<= 1){
    int x = (t >= o) ? s[t - o] : 0;
    __syncthreads();
    s[t] += x;
    __syncthreads();
  }
  bsoff[rel*512 + t] = s[t] - v;   // exclusive
}

__global__ void k_scanC(const int* __restrict__ deg2, const int* __restrict__ bsoff,
                        int* __restrict__ off2, int* __restrict__ cur2){
  int rel = blockIdx.x / NBLK, b = blockIdx.x % NBLK;
  int i = b*256 + threadIdx.x, t = threadIdx.x;
  int v = (i < NN) ? deg2[rel*NN + i] : 0;
  __shared__ int s[256];
  s[t] = v; __syncthreads();
  for (int o = 1; o < 256; o <<= 1){
    int x = (t >= o) ? s[t - o] : 0;
    __syncthreads();
    s[t] += x;
    __syncthreads();
  }
  if (i < NN){
    int o = bsoff[rel*512 + b] + s[t] - v;
    off2[rel*NN + i] = o;
    cur2[rel*NN + i] = o;
  }
}

__global__ void k_fill(const int* __restrict__ ei_pa, const int* __restrict__ ei_ap,
                       int* __restrict__ cur2,
                       int* __restrict__ col_pa, int* __restrict__ col_ap){
  int idx = blockIdx.x * 256 + threadIdx.x;
  if (idx < NE){
    int s = ei_pa[idx], d = ei_pa[NE + idx];
    int pos = atomicAdd(&cur2[d], 1);
    col_pa[pos] = s;
  } else if (idx < 2*NE){
    int e = idx - NE;
    int s = ei_ap[e], d = ei_ap[NE + e];
    int pos = atomicAdd(&cur2[NN + d], 1);
    col_ap[pos] = s;
  }
}

// ============================ weight folding ============================
// W' = A(128-col rows) @ B(wu half) -> bf16 hi/lo MFMA B-fragments at
// k-chunk offset `off`: elem = ((gkc*8+nt)*2+h)*512 + lane*8 + j,
// lane = quad*16 + (n&15), k = gkc*32 + quad*8 + j.
struct FoldDesc { const float* A; const float* B; short* T; int off; };
struct FoldArgs { FoldDesc d[8]; int rs[9]; };

__global__ void k_fold(FoldArgs fa){
  int row = blockIdx.x;
  int seg = 0;
  #pragma unroll
  for (int s = 0; s < 8; ++s) if (row >= fa.rs[s+1]) seg = s + 1;
  int m = row - fa.rs[seg];             // local k index of W'
  const float* A = fa.d[seg].A + (size_t)m * 128;
  const float* B = fa.d[seg].B;
  int n = threadIdx.x;
  float acc = 0.f;
  for (int k = 0; k < 128; ++k) acc += A[k] * B[k*128 + n];
  unsigned hb = f2bf_bits(acc);
  float hf = __uint_as_float(hb << 16);
  unsigned lb = f2bf_bits(acc - hf);
  int gkc = fa.d[seg].off + (m >> 5), quad = (m >> 3) & 3, j = m & 7;
  int lane = quad*16 + (n & 15), nt = n >> 4;
  size_t fb = (size_t)((gkc*8 + nt)*2)*512 + lane*8 + j;
  fa.d[seg].T[fb]       = (short)hb;
  fa.d[seg].T[fb + 512] = (short)lb;
}

// b' = bd@wu_top + bs@wu_bot + bu
struct BiasArgs { const float* bd[4]; const float* bs[4]; const float* wu[4];
                  const float* bu[4]; float* outb[4]; };
__global__ void k_biasfold(BiasArgs ba){
  int s = blockIdx.x, j = threadIdx.x;
  const float* wu = ba.wu[s];
  float acc = ba.bu[s][j];
  for (int k = 0; k < 128; ++k)
    acc += ba.bd[s][k] * wu[k*128 + j] + ba.bs[s][k] * wu[(128 + k)*128 + j];
  ba.outb[s][j] = acc;
}

// ============================ MFMA GEMM =================================
// C[M,128] = bnlrelu?(A1)[:,0:KC1*32] @ B[0:KC1] + A2 @ B[KC1:] (+bias)
// (+extra). B staged to LDS in 2-kc groups (32 KB). No min-wave clamp:
// natural ~120 VGPR + 64 acc -> 4 waves/SIMD -> 4 blocks/CU (LDS allows 5).
// [R6 lesson: __launch_bounds__(256,4) forced 64 VGPR -> scratch spills,
//  +27MB WRITE_SIZE, 82->110us. Never clamp below acc+staging needs.]
__global__ __launch_bounds__(256)
void k_gemm2(const float* __restrict__ A1, int lda1, int KC1,
             const float* __restrict__ bn1,
             const float* __restrict__ A2, int lda2, int KC2,
             const short* __restrict__ Bf,
             const float* __restrict__ bias, const float* __restrict__ extra,
             float* __restrict__ C, float* __restrict__ stats, int M)
{
  __shared__ __align__(16) char smem[32768];
  short* Bs = (short*)smem;

  const int tid  = threadIdx.x;
  const int wave = tid >> 6, lane = tid & 63;
  const int li   = lane & 15, quad = lane >> 4;
  const int rowT = blockIdx.x * 128 + wave * 32;
  const int KCtot = KC1 + KC2;

  f32x4v acc[2][8];
  #pragma unroll
  for (int mt = 0; mt < 2; ++mt)
    #pragma unroll
    for (int nt = 0; nt < 8; ++nt)
      acc[mt][nt] = (f32x4v){0.f, 0.f, 0.f, 0.f};

  float4 c0[2], c1[2], n0[2], n1[2];
  auto loadA = [&](int gkc, float4* p0, float4* p1){
    const float* Ab; int ld, kk; bool bn;
    if (gkc < KC1){ Ab = A1; ld = lda1; kk = gkc; bn = (bn1 != nullptr); }
    else          { Ab = A2; ld = lda2; kk = gkc - KC1; bn = false; }
    float4 sc0, sc1, sh0, sh1;
    if (bn){
      const float* bsc = bn1 + kk*32 + quad*8;
      sc0 = *(const float4*)bsc;        sc1 = *(const float4*)(bsc + 4);
      sh0 = *(const float4*)(bsc+128);  sh1 = *(const float4*)(bsc + 132);
    }
    #pragma unroll
    for (int mt = 0; mt < 2; ++mt){
      int row = rowT + mt*16 + li;
      if (row < M){
        const float* ap = Ab + (size_t)row*ld + kk*32 + quad*8;
        float4 v0 = *(const float4*)ap;
        float4 v1 = *(const float4*)(ap + 4);
        if (bn){ v0 = bn_lrelu4(v0, sc0, sh0); v1 = bn_lrelu4(v1, sc1, sh1); }
        p0[mt] = v0; p1[mt] = v1;
      } else {
        p0[mt] = make_float4(0.f,0.f,0.f,0.f);
        p1[mt] = make_float4(0.f,0.f,0.f,0.f);
      }
    }
  };
  loadA(0, c0, c1);

  for (int g = 0; g < KCtot; g += 2){
    if (g > 0) __syncthreads();          // prior group's LDS reads done
    const short* src = Bf + (size_t)g*8192;
    #pragma unroll
    for (int c2 = 0; c2 < 8; ++c2){
      int id = c2*256 + tid;             // chunk of 8 shorts, 0..2047
      *(s16x8*)(Bs + id*8) = *(const s16x8*)(src + id*8);
    }
    __syncthreads();
    #pragma unroll
    for (int kc = 0; kc < 2; ++kc){
      int gkc = g + kc;
      if (gkc + 1 < KCtot) loadA(gkc + 1, n0, n1);
      s16x8 ah[2], al[2];
      #pragma unroll
      for (int mt = 0; mt < 2; ++mt){
        float av[8] = {c0[mt].x, c0[mt].y, c0[mt].z, c0[mt].w,
                       c1[mt].x, c1[mt].y, c1[mt].z, c1[mt].w};
        split8(av, ah[mt], al[mt]);
      }
      #pragma unroll
      for (int nt = 0; nt < 8; ++nt){
        const short* bp = Bs + ((kc*8 + nt) << 10) + lane*8;
        s16x8 bh = *(const s16x8*)bp;
        s16x8 bl = *(const s16x8*)(bp + 512);
        #pragma unroll
        for (int mt = 0; mt < 2; ++mt){
          acc[mt][nt] = __builtin_amdgcn_mfma_f32_16x16x32_bf16(ah[mt], bh, acc[mt][nt], 0, 0, 0);
          acc[mt][nt] = __builtin_amdgcn_mfma_f32_16x16x32_bf16(al[mt], bh, acc[mt][nt], 0, 0, 0);
          acc[mt][nt] = __builtin_amdgcn_mfma_f32_16x16x32_bf16(ah[mt], bl, acc[mt][nt], 0, 0, 0);
        }
      }
      #pragma unroll
      for (int mt = 0; mt < 2; ++mt){ c0[mt] = n0[mt]; c1[mt] = n1[mt]; }
    }
  }

  // ---- epilogue: per-wave 16-row slab transpose (8 KB/wave) ----
  __syncthreads();                       // all LDS B reads done
  float* Cw = (float*)smem + wave*2048;  // wave-private slab
  int col4 = lane & 31;
  float4 bias4 = make_float4(0.f,0.f,0.f,0.f);
  if (bias) bias4 = ((const float4*)bias)[col4];
  float4 s1 = make_float4(0.f,0.f,0.f,0.f), s2 = s1;
  #pragma unroll
  for (int mt = 0; mt < 2; ++mt){
    #pragma unroll
    for (int r = 0; r < 4; ++r){
      int lr = quad*4 + r;               // local row 0..15
      #pragma unroll
      for (int nt = 0; nt < 8; ++nt){
        int c = nt*16 + li;
        int chunk = ((c >> 2) + 2*quad) & 31;   // rotation: 2-way max alias
        Cw[lr*128 + chunk*4 + (c & 3)] = acc[mt][nt][r];
      }
    }
    // read back (intra-wave dependence only)
    #pragma unroll
    for (int i = 0; i < 8; ++i){
      int lr = i*2 + (lane >> 5);
      int grow = rowT + mt*16 + lr;
      if (grow >= M) continue;
      int chunk = (col4 + 2*(lr >> 2)) & 31;
      float4 v = *(const float4*)(Cw + lr*128 + chunk*4);
      v.x += bias4.x; v.y += bias4.y; v.z += bias4.z; v.w += bias4.w;
      if (extra){
        float4 e = ((const float4*)(extra + (size_t)grow*128))[col4];
        v.x += e.x; v.y += e.y; v.z += e.z; v.w += e.w;
      }
      ((float4*)(C + (size_t)grow*128))[col4] = v;
      s1.x += v.x; s1.y += v.y; s1.z += v.z; s1.w += v.w;
      s2.x += v.x*v.x; s2.y += v.y*v.y; s2.z += v.z*v.z; s2.w += v.w*v.w;
    }
  }
  if (stats){
    __syncthreads();               // slabs dead; reuse smem for partials
    float* Ss = (float*)smem;      // [256 threads][8]: s1.xyzw, s2.xyzw
    ((float4*)Ss)[tid*2]     = s1;
    ((float4*)Ss)[tid*2 + 1] = s2;
    __syncthreads();
    int c = tid & 127, kind = tid >> 7;     // kind 0 = sum, 1 = sumsq
    int cc4 = c >> 2, comp = c & 3;
    float s = 0.f;
    #pragma unroll
    for (int wv = 0; wv < 4; ++wv)
      #pragma unroll
      for (int hf = 0; hf < 2; ++hf)
        s += Ss[(wv*64 + hf*32 + cc4)*8 + kind*4 + comp];
    atomicAdd(&stats[kind*128 + c], s);
  }
}

// ============================ mean-aggregate ============================
// 8 dst/block, 32 float4-lanes per dst; 4-edge unroll; optional fused
// BN+lrelu applied per gathered source row.
__global__ __launch_bounds__(256)
void k_agg(const float* __restrict__ t, const int* __restrict__ off,
           const int* __restrict__ deg, const int* __restrict__ col,
           float* __restrict__ o, const float* __restrict__ bn){
  int slot = threadIdx.x >> 5, col4 = threadIdx.x & 31;
  int d = blockIdx.x*8 + slot;
  if (d >= NN) return;
  float4 sc4, sh4;
  bool hasbn = (bn != nullptr);
  if (hasbn){ sc4 = ((const float4*)bn)[col4]; sh4 = ((const float4*)(bn+128))[col4]; }
  int s0 = off[d], cnt = deg[d];
  float4 a0 = make_float4(0.f,0.f,0.f,0.f), a1 = a0;
  int i = 0;
  for (; i + 4 <= cnt; i += 4){
    int sa = col[s0+i], sb = col[s0+i+1], sct = col[s0+i+2], sd = col[s0+i+3];
    float4 v0 = ((const float4*)(t + (size_t)sa*128))[col4];
    float4 v1 = ((const float4*)(t + (size_t)sb*128))[col4];
    float4 v2 = ((const float4*)(t + (size_t)sct*128))[col4];
    float4 v3 = ((const float4*)(t + (size_t)sd*128))[col4];
    if (hasbn){
      v0 = bn_lrelu4(v0, sc4, sh4); v1 = bn_lrelu4(v1, sc4, sh4);
      v2 = bn_lrelu4(v2, sc4, sh4); v3 = bn_lrelu4(v3, sc4, sh4);
    }
    a0.x += v0.x + v2.x; a0.y += v0.y + v2.y; a0.z += v0.z + v2.z; a0.w += v0.w + v2.w;
    a1.x += v1.x + v3.x; a1.y += v1.y + v3.y; a1.z += v1.z + v3.z; a1.w += v1.w + v3.w;
  }
  for (; i < cnt; ++i){
    int sa = col[s0+i];
    float4 v0 = ((const float4*)(t + (size_t)sa*128))[col4];
    if (hasbn) v0 = bn_lrelu4(v0, sc4, sh4);
    a0.x += v0.x; a0.y += v0.y; a0.z += v0.z; a0.w += v0.w;
  }
  float inv = 1.0f / (float)(cnt > 0 ? cnt : 1);
  float4 r;
  r.x = (a0.x + a1.x)*inv; r.y = (a0.y + a1.y)*inv;
  r.z = (a0.z + a1.z)*inv; r.w = (a0.w + a1.w)*inv;
  ((float4*)(o + (size_t)d*128))[col4] = r;
}

// ============================ batchnorm prep ============================
__global__ void k_bnprep(const float* __restrict__ stats, const float* __restrict__ g,
                         const float* __restrict__ b, float* __restrict__ sc, int M){
  int c = threadIdx.x;
  float invN = 1.0f / (float)M;
  float m  = stats[c] * invN;
  float var = stats[128 + c] * invN - m*m;
  float scale = g[c] / sqrtf(var + 1.0f);
  sc[c] = scale;
  sc[128 + c] = b[c] - m*scale;
}

// ============================ heads (fused BN+lrelu) ====================
template<int LC>
__global__ void k_head(const float* __restrict__ h, const float* __restrict__ bn,
                       const float* __restrict__ w, const float* __restrict__ b,
                       float* __restrict__ o, int M){
  __shared__ float ws[128*LC];
  __shared__ float bs[LC];
  __shared__ float bsc[256];
  for (int i = threadIdx.x; i < 128*LC; i += 256) ws[i] = w[i];
  if (threadIdx.x < LC) bs[threadIdx.x] = b[threadIdx.x];
  if (threadIdx.x < 256) bsc[threadIdx.x] = bn[threadIdx.x];
  __syncthreads();
  int r = blockIdx.x*256 + threadIdx.x;
  if (r >= M) return;
  float acc[LC];
  #pragma unroll
  for (int c = 0; c < LC; ++c) acc[c] = bs[c];
  const float4* hr = (const float4*)(h + (size_t)r*128);
  for (int k4 = 0; k4 < 32; ++k4){
    float4 v = hr[k4];
    float4 sc = ((const float4*)bsc)[k4];
    float4 sh = ((const float4*)bsc)[32 + k4];
    v = bn_lrelu4(v, sc, sh);
    int k = k4*4;
    #pragma unroll
    for (int c = 0; c < LC; ++c)
      acc[c] += v.x*ws[k*LC+c] + v.y*ws[(k+1)*LC+c] + v.z*ws[(k+2)*LC+c] + v.w*ws[(k+3)*LC+c];
  }
  #pragma unroll
  for (int c = 0; c < LC; ++c) o[(size_t)r*LC + c] = acc[c];
}

// ============================ launch ====================================
extern "C" void kernel_launch(void* const* d_in, const int* in_sizes, int n_in,
                              void* d_out, int out_size, void* d_ws, size_t ws_size,
                              hipStream_t stream) {
  const float* x_author = (const float*)d_in[0];   // [NN,256]
  const float* x_paper  = (const float*)d_in[1];   // [NN,128]
  const int*   ei_pa    = (const int*)d_in[2];     // [2,NE]
  const int*   ei_ap    = (const int*)d_in[3];     // [2,NE]

  char* p = (char*)d_ws;
  auto alloc = [&](size_t bytes) -> void* {
    void* r = (void*)p; p += (bytes + 255) & ~(size_t)255; return r;
  };
  // combined fragment tables (bf16 hi/lo, 16 KB per k-chunk):
  short* T_l1a  = (short*)alloc(12u*16384);  // [x_author(8) | agg_pa(4)]
  short* T_l1ps = (short*)alloc( 8u*16384);  // src transform: x_author @ Ws'
  short* T_l1pd = (short*)alloc( 4u*16384);  // dst: x_paper @ Wd'
  short* T_l2a  = (short*)alloc( 8u*16384);  // [h_a(4) | agg(4)]
  short* T_l2p  = (short*)alloc( 8u*16384);
  float* w1a_b = (float*)alloc(128*4);      float* w1p_b = (float*)alloc(128*4);
  float* w2a_b = (float*)alloc(128*4);      float* w2p_b = (float*)alloc(128*4);
  float* stats4 = (float*)alloc(4*256*4);   // 4 BN instances (sum/sumsq)
  float* bnsc4  = (float*)alloc(4*256*4);   // 4 BN instances (scale/shift)
  int* deg2  = (int*)alloc(2*NN*4);
  int* off2  = (int*)alloc(2*NN*4);
  int* cur2  = (int*)alloc(2*NN*4);
  int* col_pa = (int*)alloc(NE*4);
  int* col_ap = (int*)alloc(NE*4);
  int* bsum  = (int*)alloc(1024*4);
  int* bsoff = (int*)alloc(1024*4);
  const size_t NB = (size_t)NN * 128;
  float* B1 = (float*)alloc(NB*4);  // h_author L1 (pre-BN)
  float* B2 = (float*)alloc(NB*4);  // h_paper L1 (pre-BN)
  float* B3 = (float*)alloc(NB*4);  // src transform (l1p) / h_a2 / h_p2
  float* B4 = (float*)alloc(NB*4);  // agg buffer

  // ---- CSR build ----
  hipMemsetAsync(deg2, 0, 2*NN*4, stream);
  hipMemsetAsync(stats4, 0, 4*256*4, stream);
  k_count<<<(2*NE + 255)/256, 256, 0, stream>>>(ei_pa, ei_ap, deg2);
  k_bsum <<<2*NBLK, 256, 0, stream>>>(deg2, bsum);
  k_bscan<<<2, 512, 0, stream>>>(bsum, bsoff);
  k_scanC<<<2*NBLK, 256, 0, stream>>>(deg2, bsoff, off2, cur2);
  k_fill <<<(2*NE + 255)/256, 256, 0, stream>>>(ei_pa, ei_ap, cur2, col_pa, col_ap);

  // ---- fold weights into combined tables ----
  FoldArgs fa;
  const float* wu1a = (const float*)d_in[8];
  const float* wu1p = (const float*)d_in[14];
  const float* wu2a = (const float*)d_in[20];
  const float* wu2p = (const float*)d_in[26];
  fa.d[0] = { (const float*)d_in[6],  wu1a,           T_l1a,  0 };  // wd_l1a (256)
  fa.d[1] = { (const float*)d_in[4],  wu1a + 128*128, T_l1a,  8 };  // ws_l1a (128)
  fa.d[2] = { (const float*)d_in[10], wu1p + 128*128, T_l1ps, 0 };  // ws_l1p (256)
  fa.d[3] = { (const float*)d_in[12], wu1p,           T_l1pd, 0 };  // wd_l1p (128)
  fa.d[4] = { (const float*)d_in[18], wu2a,           T_l2a,  0 };  // wd_l2a (128)
  fa.d[5] = { (const float*)d_in[16], wu2a + 128*128, T_l2a,  4 };  // ws_l2a (128)
  fa.d[6] = { (const float*)d_in[24], wu2p,           T_l2p,  0 };  // wd_l2p (128)
  fa.d[7] = { (const float*)d_in[22], wu2p + 128*128, T_l2p,  4 };  // ws_l2p (128)
  int rows[8] = {256,128,256,128,128,128,128,128};
  fa.rs[0] = 0;
  for (int i = 0; i < 8; ++i) fa.rs[i+1] = fa.rs[i] + rows[i];
  k_fold<<<fa.rs[8], 128, 0, stream>>>(fa);

  BiasArgs ba;
  ba.bd[0]=(const float*)d_in[7];  ba.bs[0]=(const float*)d_in[5];  ba.wu[0]=wu1a; ba.bu[0]=(const float*)d_in[9];  ba.outb[0]=w1a_b;
  ba.bd[1]=(const float*)d_in[13]; ba.bs[1]=(const float*)d_in[11]; ba.wu[1]=wu1p; ba.bu[1]=(const float*)d_in[15]; ba.outb[1]=w1p_b;
  ba.bd[2]=(const float*)d_in[19]; ba.bs[2]=(const float*)d_in[17]; ba.wu[2]=wu2a; ba.bu[2]=(const float*)d_in[21]; ba.outb[2]=w2a_b;
  ba.bd[3]=(const float*)d_in[25]; ba.bs[3]=(const float*)d_in[23]; ba.wu[3]=wu2p; ba.bu[3]=(const float*)d_in[27]; ba.outb[3]=w2p_b;
  k_biasfold<<<4, 128, 0, stream>>>(ba);

  const int GG = (NN + 127)/128;   // 782
  const int AGG_GRID = (NN + 7)/8; // 12500
  const int* off_pa = off2;        const int* deg_pa = deg2;
  const int* off_ap = off2 + NN;   const int* deg_ap = deg2 + NN;
  float* st_a1 = stats4;       float* st_p1 = stats4 + 256;
  float* st_a2 = stats4 + 512; float* st_p2 = stats4 + 768;
  float* sc_a1 = bnsc4;        float* sc_p1 = bnsc4 + 256;
  float* sc_a2 = bnsc4 + 512;  float* sc_p2 = bnsc4 + 768;

  // ---- layer 1, author (p2a): agg-first ----
  k_agg<<<AGG_GRID, 256, 0, stream>>>(x_paper, off_pa, deg_pa, col_pa, B4, nullptr);
  k_gemm2<<<GG, 256, 0, stream>>>(x_author, 256, 8, nullptr, B4, 128, 4, T_l1a,
                                  w1a_b, nullptr, B1, st_a1, NN);
  k_bnprep<<<1, 128, 0, stream>>>(st_a1, (const float*)d_in[28], (const float*)d_in[29], sc_a1, NN);

  // ---- layer 1, paper (a2p): transform-first (src is 256-wide) ----
  k_gemm2<<<GG, 256, 0, stream>>>(x_author, 256, 8, nullptr, nullptr, 0, 0, T_l1ps,
                                  nullptr, nullptr, B3, nullptr, NN);
  k_agg<<<AGG_GRID, 256, 0, stream>>>(B3, off_ap, deg_ap, col_ap, B4, nullptr);
  k_gemm2<<<GG, 256, 0, stream>>>(x_paper, 128, 4, nullptr, nullptr, 0, 0, T_l1pd,
                                  w1p_b, B4, B2, st_p1, NN);
  k_bnprep<<<1, 128, 0, stream>>>(st_p1, (const float*)d_in[30], (const float*)d_in[31], sc_p1, NN);

  // ---- layer 2, author (p2a): agg-first on bn(h_paper) ----
  k_agg<<<AGG_GRID, 256, 0, stream>>>(B2, off_pa, deg_pa, col_pa, B4, sc_p1);
  k_gemm2<<<GG, 256, 0, stream>>>(B1, 128, 4, sc_a1, B4, 128, 4, T_l2a,
                                  w2a_b, nullptr, B3, st_a2, NN);
  k_bnprep<<<1, 128, 0, stream>>>(st_a2, (const float*)d_in[32], (const float*)d_in[33], sc_a2, NN);
  k_head<4><<<(NN + 255)/256, 256, 0, stream>>>(B3, sc_a2, (const float*)d_in[36],
                                                (const float*)d_in[37], (float*)d_out, NN);

  // ---- layer 2, paper (a2p): agg-first on bn(h_author) ----
  k_agg<<<AGG_GRID, 256, 0, stream>>>(B1, off_ap, deg_ap, col_ap, B4, sc_a1);
  k_gemm2<<<GG, 256, 0, stream>>>(B2, 128, 4, sc_p1, B4, 128, 4, T_l2p,
                                  w2p_b, nullptr, B3, st_p2, NN);
  k_bnprep<<<1, 128, 0, stream>>>(st_p2, (const float*)d_in[34], (const float*)d_in[35], sc_p2, NN);
  k_head<7><<<(NN + 255)/256, 256, 0, stream>>>(B3, sc_p2, (const float*)d_in[38],
                                                (const float*)d_in[39], (float*)d_out + (size_t)NN*4, NN);
}